// Round 7
// baseline (93.951 us; speedup 1.0000x reference)
//
#include <hip/hip_runtime.h>

// ReflectionRayTracer: 8192 rays x 2048 quad surfaces. out[ray][surf] = t*mask.
//
// R12: R9 (plain v2f stores) + PRE-ZERO the output with a dedicated fill
// kernel that mimics rocclr fillBufferAligned (256-thr blocks, dwordx4,
// 1KB/wave linear, store-only).
//  Evidence chain: R8 warm re-run = 12.6us (lines resident-dirty => no
//  allocation cost). Cold trace ~37us. R7 (instructions), R9 (order),
//  R10/R11 (nt / sc0 sc1 nt policy) all null => the ~24us cold penalty is
//  per-line allocation/eviction work that store-POLICY cannot remove.
//  New R11b observation: harness fills do 268MB of the SAME dirty-cache
//  allocation+eviction work in 45us (~6 TB/s) — a dense store-only kernel
//  absorbs the cost; our compute-interleaved store stream does not.
//  Fix: move the allocation cost into a 64MiB store-only pre-zero pass
//  (~11-14us at fill rate), then the trace hits OUR resident-dirty lines =
//  R8's warm regime (~13us). Trace overwrites every element => correctness
//  unchanged; stream order serializes the kernels.
//  Math identical to R9 => absmax 4.03125.

#define N_RAYS 8192
#define N_SURF 2048
constexpr int RPB = 32;    // rays (rows) per block
constexpr int SPT = 2;     // surfaces per thread
constexpr int TPB = 1024;  // threads per block: TPB*SPT == N_SURF (full row)

typedef float v2f __attribute__((ext_vector_type(2)));
#define FMA2(a, b, c) __builtin_elementwise_fma((a), (b), (c))

__device__ __forceinline__ float safef(float x) {
    return (x == 0.0f) ? 1e-18f : x;   // jnp.where(x==0, EPS, x)
}

// ---- pre-zero: rocclr-fill-style dense store stream over the output ----
__global__ __launch_bounds__(256) void zerofill_kernel(float4* __restrict__ p)
{
    constexpr int n16 = (size_t)N_RAYS * N_SURF * 4 / 16;  // 4,194,304 float4s
    const int stride = gridDim.x * 256;
    const float4 z = {0.0f, 0.0f, 0.0f, 0.0f};
    for (int i = blockIdx.x * 256 + threadIdx.x; i < n16; i += stride)
        p[i] = z;   // global_store_dwordx4, 1KB/wave linear
}

// Per-surface coefficients (identical formula sequence to R9/R10/R11).
__device__ __forceinline__ void surf_coeffs(const float* __restrict__ V, int s,
                                            float* __restrict__ c)
{
    const float4 p0 = *(const float4*)(V + (size_t)s * 12);
    const float4 p1 = *(const float4*)(V + (size_t)s * 12 + 4);
    const float4 p2 = *(const float4*)(V + (size_t)s * 12 + 8);
    const float ax = p0.x, ay = p0.y, az = p0.z;       // a = V[s][0]
    const float bx = p0.w, by = p1.x, bz = p1.y;       // b = V[s][1]
    const float cx = p1.z, cy = p1.w, cz = p2.x;       // c = V[s][2]
    const float wx = p2.y, wy = p2.z, wz = p2.w;       // V[s][3]

    const float e0x = bx - ax, e0y = by - ay, e0z = bz - az;
    const float e1x = cx - ax, e1y = cy - ay, e1z = cz - az;
    const float nx = e0y * e1z - e0z * e1y;
    const float ny = e0z * e1x - e0x * e1z;
    const float nz = e0x * e1y - e0y * e1x;
    const float rn = __builtin_amdgcn_rsqf(fmaf(nx, nx, fmaf(ny, ny, nz * nz)));
    const float vx = nx * rn, vy = ny * rn, vz = nz * rn;
    const float k = -fmaf(vx, wx, fmaf(vy, wy, vz * wz));

    const float B  = ax * bz - az * bx;
    const float D  = ax * by - ay * bx;                 // G == D
    const float E  = ax * cz - az * cx;
    const float P  = ay * cx - ax * cy;
    const float F  = B * P;
    const float rden = __builtin_amdgcn_rcpf(safef(D * fmaf(E, D, F)));
    const float rD   = __builtin_amdgcn_rcpf(safef(D));
    const float rAX  = __builtin_amdgcn_rcpf(safef(ax));

    const float DB = D * B, DD = D * D;
    const float g0 = (DB * ay - DD * az) * rden;
    const float g1 = -(DB * ax) * rden;
    const float g2 = (DD * ax) * rden;
    const float bp  = P * rD;
    const float bb0 = fmaf(bp, g0, -ay * rD);
    const float bb1 = fmaf(bp, g1,  ax * rD);
    const float bb2 = bp * g2;
    const float ab = -bx * rAX, ac = -cx * rAX;
    const float aa0 = fmaf(ab, bb0, fmaf(ac, g0, rAX));
    const float aa1 = fmaf(ab, bb1, ac * g1);
    const float aa2 = fmaf(ab, bb2, ac * g2);

    c[0] = vx;  c[1] = vy;  c[2] = vz;  c[3] = k;
    c[4] = g0;  c[5] = g1;  c[6] = g2;
    c[7] = bb0; c[8] = bb1; c[9] = bb2;
    c[10] = aa0; c[11] = aa1; c[12] = aa2;
}

__global__ __launch_bounds__(TPB, 4) void trace_kernel(
    const float* __restrict__ o, const float* __restrict__ dr,
    const float* __restrict__ V, float* __restrict__ out)
{
    const int s0 = threadIdx.x * SPT;   // surface pair within the row

    // ---- inline preamble: coeffs for 2 adjacent surfaces, packed v2f ----
    float cA[13], cB[13];
    surf_coeffs(V, s0, cA);
    surf_coeffs(V, s0 + 1, cB);
    const v2f vx  = {cA[0],  cB[0]};
    const v2f vy  = {cA[1],  cB[1]};
    const v2f vz  = {cA[2],  cB[2]};
    const v2f kk  = {cA[3],  cB[3]};
    const v2f g0  = {cA[4],  cB[4]};
    const v2f g1  = {cA[5],  cB[5]};
    const v2f g2  = {cA[6],  cB[6]};
    const v2f bb0 = {cA[7],  cB[7]};
    const v2f bb1 = {cA[8],  cB[8]};
    const v2f bb2 = {cA[9],  cB[9]};
    const v2f aa0 = {cA[10], cB[10]};
    const v2f aa1 = {cA[11], cB[11]};
    const v2f aa2 = {cA[12], cB[12]};

    // ---- ray loop: block writes 32 consecutive rows = 256KB linear span ----
    const int ray0 = blockIdx.x * RPB;
    float* outp = out + (size_t)ray0 * N_SURF + s0;

#pragma unroll 4
    for (int i = 0; i < RPB; ++i) {
        const int ray = ray0 + i;
        // Wave-uniform ray loads -> scalar (SMEM) loads.
        const float o0 = o[ray * 3 + 0], o1 = o[ray * 3 + 1], o2 = o[ray * 3 + 2];
        const float d0 = dr[ray * 3 + 0], d1 = dr[ray * 3 + 1], d2 = dr[ray * 3 + 2];
        const v2f o0v = o0, o1v = o1, o2v = o2;
        const v2f d0v = d0, d1v = d1, d2v = d2;

        const v2f vo_k = FMA2(o0v, vx, FMA2(o1v, vy, FMA2(o2v, vz, kk))); // k + v.o
        const v2f vd   = FMA2(d0v, vx, FMA2(d1v, vy, d2v * vz));
        v2f rv;
        rv.x = __builtin_amdgcn_rcpf(vd.x);
        rv.y = __builtin_amdgcn_rcpf(vd.y);
        const v2f t = -vo_k * rv;

        const v2f rx = FMA2(t, d0v, o0v);
        const v2f ry = FMA2(t, d1v, o1v);
        const v2f rz = FMA2(t, d2v, o2v);

        const v2f gam = FMA2(g0,  rx, FMA2(g1,  ry, g2  * rz));
        const v2f bet = FMA2(bb0, rx, FMA2(bb1, ry, bb2 * rz));
        const v2f alp = FMA2(aa0, rx, FMA2(aa1, ry, aa2 * rz));

        const float mnx = fminf(fminf(bet.x, gam.x), alp.x);  // v_min3_f32
        const float mny = fminf(fminf(bet.y, gam.y), alp.y);
        v2f res;
        res.x = (mnx > 0.0f) ? t.x : 0.0f;
        res.y = (mny > 0.0f) ? t.y : 0.0f;
        // Plain writeback store: hits OUR resident-dirty zero lines (warm
        // regime, R8-measured 12.6us) — allocation cost was paid by zerofill.
        *(v2f*)(outp + (size_t)i * N_SURF) = res;
    }
}

extern "C" void kernel_launch(void* const* d_in, const int* in_sizes, int n_in,
                              void* d_out, int out_size, void* d_ws, size_t ws_size,
                              hipStream_t stream) {
    const float* o  = (const float*)d_in[0];
    const float* dr = (const float*)d_in[1];
    const float* V  = (const float*)d_in[2];
    float* out = (float*)d_out;

    zerofill_kernel<<<dim3(2048), dim3(256), 0, stream>>>((float4*)out);
    trace_kernel<<<dim3(N_RAYS / RPB), dim3(TPB), 0, stream>>>(o, dr, V, out);
}

// Round 8
// 83.566 us; speedup vs baseline: 1.1243x; 1.1243x over previous
//
#include <hip/hip_runtime.h>

// ReflectionRayTracer: 8192 rays x 2048 quad surfaces. out[ray][surf] = t*mask.
//
// R13 = R11b REVERT (best measured: 82.2us). R12's payer-shift zerofill
// regressed (+11.8us): the ~37us first-touch toll after the harness's 256MiB
// poison is PAYER-INVARIANT — moving it into a dense store-only pass just adds
// a second kernel's execution on top.
//
// Final ledger (all A/B on MI355X):
//   R7  instruction count (pk-f32, half stores)   -> null
//   R8  double-launch probe: warm re-touch = 12.6us, cold = ~37us
//   R9  linear 256KB/block store spans            -> null
//   R10 __builtin_nontemporal_store               -> -2us
//   R11b global_store_dwordx2 sc0 sc1 nt          -> -1us (best: 82.2us)
//   R12 pre-zero payer shift                      -> +11.8us
// Structural floor: harness poison fill (~45us) + 64MiB first-touch toll
// (~37us, MALL victim-eviction scatter, invariant under store policy/order/
// density/width/payer) ~= 82us. R11b measured 82.2us => at the floor.

#define N_RAYS 8192
#define N_SURF 2048
constexpr int RPB = 32;    // rays (rows) per block
constexpr int SPT = 2;     // surfaces per thread
constexpr int TPB = 1024;  // threads per block: TPB*SPT == N_SURF (full row)

typedef float v2f __attribute__((ext_vector_type(2)));
#define FMA2(a, b, c) __builtin_elementwise_fma((a), (b), (c))

__device__ __forceinline__ float safef(float x) {
    return (x == 0.0f) ? 1e-18f : x;   // jnp.where(x==0, EPS, x)
}

// Per-surface coefficients (identical formula sequence since R9).
__device__ __forceinline__ void surf_coeffs(const float* __restrict__ V, int s,
                                            float* __restrict__ c)
{
    const float4 p0 = *(const float4*)(V + (size_t)s * 12);
    const float4 p1 = *(const float4*)(V + (size_t)s * 12 + 4);
    const float4 p2 = *(const float4*)(V + (size_t)s * 12 + 8);
    const float ax = p0.x, ay = p0.y, az = p0.z;       // a = V[s][0]
    const float bx = p0.w, by = p1.x, bz = p1.y;       // b = V[s][1]
    const float cx = p1.z, cy = p1.w, cz = p2.x;       // c = V[s][2]
    const float wx = p2.y, wy = p2.z, wz = p2.w;       // V[s][3]

    const float e0x = bx - ax, e0y = by - ay, e0z = bz - az;
    const float e1x = cx - ax, e1y = cy - ay, e1z = cz - az;
    const float nx = e0y * e1z - e0z * e1y;
    const float ny = e0z * e1x - e0x * e1z;
    const float nz = e0x * e1y - e0y * e1x;
    const float rn = __builtin_amdgcn_rsqf(fmaf(nx, nx, fmaf(ny, ny, nz * nz)));
    const float vx = nx * rn, vy = ny * rn, vz = nz * rn;
    const float k = -fmaf(vx, wx, fmaf(vy, wy, vz * wz));

    const float B  = ax * bz - az * bx;
    const float D  = ax * by - ay * bx;                 // G == D
    const float E  = ax * cz - az * cx;
    const float P  = ay * cx - ax * cy;
    const float F  = B * P;
    const float rden = __builtin_amdgcn_rcpf(safef(D * fmaf(E, D, F)));
    const float rD   = __builtin_amdgcn_rcpf(safef(D));
    const float rAX  = __builtin_amdgcn_rcpf(safef(ax));

    const float DB = D * B, DD = D * D;
    const float g0 = (DB * ay - DD * az) * rden;
    const float g1 = -(DB * ax) * rden;
    const float g2 = (DD * ax) * rden;
    const float bp  = P * rD;
    const float bb0 = fmaf(bp, g0, -ay * rD);
    const float bb1 = fmaf(bp, g1,  ax * rD);
    const float bb2 = bp * g2;
    const float ab = -bx * rAX, ac = -cx * rAX;
    const float aa0 = fmaf(ab, bb0, fmaf(ac, g0, rAX));
    const float aa1 = fmaf(ab, bb1, ac * g1);
    const float aa2 = fmaf(ab, bb2, ac * g2);

    c[0] = vx;  c[1] = vy;  c[2] = vz;  c[3] = k;
    c[4] = g0;  c[5] = g1;  c[6] = g2;
    c[7] = bb0; c[8] = bb1; c[9] = bb2;
    c[10] = aa0; c[11] = aa1; c[12] = aa2;
}

__global__ __launch_bounds__(TPB, 4) void trace_kernel(
    const float* __restrict__ o, const float* __restrict__ dr,
    const float* __restrict__ V, float* __restrict__ out)
{
    const int s0 = threadIdx.x * SPT;   // surface pair within the row

    // ---- inline preamble: coeffs for 2 adjacent surfaces, packed v2f ----
    float cA[13], cB[13];
    surf_coeffs(V, s0, cA);
    surf_coeffs(V, s0 + 1, cB);
    const v2f vx  = {cA[0],  cB[0]};
    const v2f vy  = {cA[1],  cB[1]};
    const v2f vz  = {cA[2],  cB[2]};
    const v2f kk  = {cA[3],  cB[3]};
    const v2f g0  = {cA[4],  cB[4]};
    const v2f g1  = {cA[5],  cB[5]};
    const v2f g2  = {cA[6],  cB[6]};
    const v2f bb0 = {cA[7],  cB[7]};
    const v2f bb1 = {cA[8],  cB[8]};
    const v2f bb2 = {cA[9],  cB[9]};
    const v2f aa0 = {cA[10], cB[10]};
    const v2f aa1 = {cA[11], cB[11]};
    const v2f aa2 = {cA[12], cB[12]};

    // ---- ray loop: block writes 32 consecutive rows = 256KB linear span ----
    const int ray0 = blockIdx.x * RPB;
    float* outp = out + (size_t)ray0 * N_SURF + s0;

#pragma unroll 4
    for (int i = 0; i < RPB; ++i) {
        const int ray = ray0 + i;
        // Wave-uniform ray loads -> scalar (SMEM) loads.
        const float o0 = o[ray * 3 + 0], o1 = o[ray * 3 + 1], o2 = o[ray * 3 + 2];
        const float d0 = dr[ray * 3 + 0], d1 = dr[ray * 3 + 1], d2 = dr[ray * 3 + 2];
        const v2f o0v = o0, o1v = o1, o2v = o2;
        const v2f d0v = d0, d1v = d1, d2v = d2;

        const v2f vo_k = FMA2(o0v, vx, FMA2(o1v, vy, FMA2(o2v, vz, kk))); // k + v.o
        const v2f vd   = FMA2(d0v, vx, FMA2(d1v, vy, d2v * vz));
        v2f rv;
        rv.x = __builtin_amdgcn_rcpf(vd.x);
        rv.y = __builtin_amdgcn_rcpf(vd.y);
        const v2f t = -vo_k * rv;

        const v2f rx = FMA2(t, d0v, o0v);
        const v2f ry = FMA2(t, d1v, o1v);
        const v2f rz = FMA2(t, d2v, o2v);

        const v2f gam = FMA2(g0,  rx, FMA2(g1,  ry, g2  * rz));
        const v2f bet = FMA2(bb0, rx, FMA2(bb1, ry, bb2 * rz));
        const v2f alp = FMA2(aa0, rx, FMA2(aa1, ry, aa2 * rz));

        const float mnx = fminf(fminf(bet.x, gam.x), alp.x);  // v_min3_f32
        const float mny = fminf(fminf(bet.y, gam.y), alp.y);
        v2f res;
        res.x = (mnx > 0.0f) ? t.x : 0.0f;
        res.y = (mny > 0.0f) ? t.y : 0.0f;

        // Streaming store (best measured config): system-scope + nt.
        v2f* p = (v2f*)(outp + (size_t)i * N_SURF);
        asm volatile("global_store_dwordx2 %0, %1, off sc0 sc1 nt"
                     :: "v"(p), "v"(res) : "memory");
    }
}

extern "C" void kernel_launch(void* const* d_in, const int* in_sizes, int n_in,
                              void* d_out, int out_size, void* d_ws, size_t ws_size,
                              hipStream_t stream) {
    const float* o  = (const float*)d_in[0];
    const float* dr = (const float*)d_in[1];
    const float* V  = (const float*)d_in[2];
    float* out = (float*)d_out;

    trace_kernel<<<dim3(N_RAYS / RPB), dim3(TPB), 0, stream>>>(o, dr, V, out);
}